// Round 6
// baseline (139.945 us; speedup 1.0000x reference)
//
#include <hip/hip_runtime.h>
#include <cfloat>

// ---------------------------------------------------------------------------
// VQ-VAE vector quantizer forward (MI355X / gfx950)
//   x        [32][64][64][64] f32   (B, D, H, W)
//   codebook [1024][64] f32
// out: x_q transposed back to [B,D,H,W] (8388608 f32)  +  loss scalar (1 f32)
//
// argmin_k ||x - c_k||^2  ==  argmax_k (x . c_k - ||c_k||^2/2)
// Sum_p SSE_p = Sum x^2  -  2 * Sum_p (best_score_p - 1),
//   where score = dot + 1 - ||c||^2/2 (C-init trick, packed-u32 argmax).
//
// R6: persistent 16-wave block (1024 thr), 1 block/CU (grid=256), 8 rows per
// block. Each wave holds its 4 B-tiles (64 codes) + hneg + code consts in
// REGISTERS for the whole kernel -> zero B traffic in steady state. Per row:
// cooperative coalesced x-stage (issued under previous row's epilogue) into
// LDS A-fragments; 16-wave MFMA + packed sortable-u32 argmax (R5-proven);
// LDS merge -> idx -> coalesced transposed output. Loss needs no per-position
// xsq: staging threads accumulate Sum x^2, merge lanes accumulate Sum(vt-1).
// ---------------------------------------------------------------------------

#define DD    64
#define HHWW  4096         // H*W
#define KC    1024
#define NBLK2 256          // persistent blocks (1 per CU)
#define RPB   8            // rows per block (2048 / 256)
#define NPOSD 8388608.0f   // N * D

typedef __bf16  bf16x8 __attribute__((ext_vector_type(8)));
typedef float   f32x4  __attribute__((ext_vector_type(4)));

__device__ __forceinline__ unsigned short bf16_bits(float f) {
  unsigned u = __float_as_uint(f);
  return (unsigned short)((u + 0x7FFFu + ((u >> 16) & 1u)) >> 16);  // RNE
}

// --- precompute: fragment-ordered bf16 codebook + (1 - ||c||^2/2) ----------
__global__ __launch_bounds__(256) void vq_pre(
    const float* __restrict__ cb,          // [1024][64]
    unsigned short* __restrict__ cb_frag,  // [tile=64][kk=2][lane=64][e=8]
    float* __restrict__ hneg1)             // [1024] : 1 - ||c||^2/2
{
  int k = blockIdx.x * 256 + threadIdx.x;
  if (k >= KC) return;
  float c[DD];
  float sum = 0.f;
#pragma unroll
  for (int d = 0; d < DD; ++d) { c[d] = cb[k * DD + d]; sum += c[d] * c[d]; }
  hneg1[k] = 1.0f - 0.5f * sum;
  int t = k >> 4, l15 = k & 15;
#pragma unroll
  for (int kk = 0; kk < 2; ++kk)
#pragma unroll
    for (int g = 0; g < 4; ++g)
#pragma unroll
      for (int e = 0; e < 8; ++e)
        cb_frag[(((t * 2 + kk) * 64) + (g * 16 + l15)) * 8 + e] =
            bf16_bits(c[kk * 32 + g * 8 + e]);
}

// --- main: persistent fused distance-GEMM + argmin + loss + output ---------
__global__ __launch_bounds__(1024, 1) void vq_main(
    const float* __restrict__ x,
    const unsigned short* __restrict__ cb_frag,
    const float* __restrict__ hneg1,
    const float* __restrict__ cb,
    float* __restrict__ out,
    float* __restrict__ partials)
{
  __shared__ unsigned short alds[4096];   // 8 KB: A-frags of current row
  __shared__ unsigned int   cand[16][64]; // 4 KB: per-wave winners
  __shared__ int            idx_lds[64];
  __shared__ float          xred[16];

  const int tid  = threadIdx.x;
  const int wv   = tid >> 6;     // 0..15
  const int lane = tid & 63;
  const int l15  = lane & 15;
  const int g    = lane >> 4;

  // ---- prologue: this wave's 4 B-tiles + hneg + code base -> REGISTERS ----
  bf16x8 breg[4][2];
  float  mh[4];
#pragma unroll
  for (int i = 0; i < 4; ++i) {
    const int ctg = wv * 4 + i;                       // global code tile
    const char* bp = (const char*)cb_frag + (size_t)ctg * 2048 + (size_t)lane * 16;
    breg[i][0] = *(const bf16x8*)(bp);                // kk=0
    breg[i][1] = *(const bf16x8*)(bp + 1024);         // kk=1
    mh[i] = hneg1[ctg * 16 + l15];                    // 1 - ||c||^2/2
  }
  const unsigned int MASK = 0xFFFFFC00u;
  const int c0 = 1023 - wv * 64 - l15;                // codec = c0 - i*16

  // ---- stage mapping: thread covers (w=lane, d = sd0..sd0+3) ----
  const int so  = wv >> 1;                  // d-octet 0..7  (kk = so>>2, g = so&3)
  const int sh  = wv & 1;                   // e-half
  const int sd0 = so * 8 + sh * 4;
  // frag elem offset: pt*1024 + kk*512 + (g*16 + l15)*8 + e  (pt/l15 from w)
  const int woff = (lane >> 4) * 1024 + (so >> 2) * 512 +
                   ((so & 3) * 16 + (lane & 15)) * 8 + sh * 4;

  float xacc  = 0.f;   // Sum x^2 (every (w,d) exactly once per row)
  float vtacc = 0.f;   // Sum (vt - 1), merge lanes only

  const int row0 = blockIdx.x * RPB;

  // preload row 0's x slice into registers
  float px[4];
  {
    const float* xb = x + (size_t)(row0 >> 6) * DD * HHWW + (row0 & 63) * 64;
#pragma unroll
    for (int j = 0; j < 4; ++j) px[j] = xb[(size_t)(sd0 + j) * HHWW + lane];
  }

  for (int r = 0; r < RPB; ++r) {
    const int row = row0 + r;
    const int b = row >> 6, h = row & 63;

    // ---- stage: convert + ds_write_b64 into frag layout; Sum x^2 ----
    {
      float s = 0.f;
      unsigned int lo, hi;
      unsigned short u0, u1, u2, u3;
      s += px[0] * px[0]; u0 = bf16_bits(px[0]);
      s += px[1] * px[1]; u1 = bf16_bits(px[1]);
      s += px[2] * px[2]; u2 = bf16_bits(px[2]);
      s += px[3] * px[3]; u3 = bf16_bits(px[3]);
      xacc += s;
      lo = (unsigned int)u0 | ((unsigned int)u1 << 16);
      hi = (unsigned int)u2 | ((unsigned int)u3 << 16);
      uint2 wval; wval.x = lo; wval.y = hi;
      *(uint2*)(&alds[woff]) = wval;                   // 8B, 8-aligned
    }
    __syncthreads();                                   // bar1: A ready

    // ---- compute: 4 pos-tiles x 4 code-tiles, packed-u32 argmax ----
    unsigned int best[4][4];
#pragma unroll
    for (int pt = 0; pt < 4; ++pt)
#pragma unroll
      for (int rr = 0; rr < 4; ++rr) best[pt][rr] = 0u;

#pragma unroll
    for (int pt = 0; pt < 4; ++pt) {
      const bf16x8 a0 = *(const bf16x8*)(&alds[pt * 1024 + lane * 8]);
      const bf16x8 a1 = *(const bf16x8*)(&alds[pt * 1024 + 512 + lane * 8]);
#pragma unroll
      for (int i = 0; i < 4; ++i) {
        f32x4 acc = {mh[i], mh[i], mh[i], mh[i]};
        acc = __builtin_amdgcn_mfma_f32_16x16x32_bf16(a0, breg[i][0], acc, 0, 0, 0);
        acc = __builtin_amdgcn_mfma_f32_16x16x32_bf16(a1, breg[i][1], acc, 0, 0, 0);
        const unsigned int codec = (unsigned int)(c0 - i * 16);
#pragma unroll
        for (int rr = 0; rr < 4; ++rr) {   // C/D: col=l15(code), row=g*4+rr(pos)
          unsigned int p = (__float_as_uint(acc[rr]) & MASK) | codec;
          best[pt][rr] = best[pt][rr] > p ? best[pt][rr] : p;
        }
      }
    }

    // cross-lane max over the 16 code columns (l15)
#pragma unroll
    for (int pt = 0; pt < 4; ++pt)
#pragma unroll
      for (int rr = 0; rr < 4; ++rr) {
        unsigned int v = best[pt][rr];
#pragma unroll
        for (int m = 1; m < 16; m <<= 1) {
          unsigned int vo = __shfl_xor(v, m, 64);
          v = v > vo ? v : vo;
        }
        if (l15 == 0) cand[wv][pt * 16 + g * 4 + rr] = v;
      }
    __syncthreads();                                   // bar2: cand ready

    // ---- merge 16 wave-candidates per position; accumulate loss term ----
    if (tid < 64) {
      unsigned int v = cand[0][tid];
#pragma unroll
      for (int q = 1; q < 16; ++q) {
        unsigned int o = cand[q][tid];
        v = v > o ? v : o;
      }
      idx_lds[tid] = 1023 - (int)(v & 1023u);
      vtacc += __uint_as_float(v & MASK) - 1.0f;       // dot - csq/2 (trunc)
    }
    __syncthreads();                                   // bar3: idx ready

    // ---- issue next row's x loads early (hide under epilogue) ----
    if (r + 1 < RPB) {
      const int rown = row + 1;
      const float* xbn = x + (size_t)(rown >> 6) * DD * HHWW + (rown & 63) * 64;
#pragma unroll
      for (int j = 0; j < 4; ++j) px[j] = xbn[(size_t)(sd0 + j) * HHWW + lane];
    }

    // ---- output: thread = (w=lane, dchunk=wv); gather cb row, store x4 ----
    {
      const int myidx = idx_lds[lane];
      const float4 cv = *(const float4*)(cb + (size_t)myidx * DD + wv * 4);
      float* ob = out + (size_t)b * DD * HHWW + h * 64;
      ob[(size_t)(wv * 4 + 0) * HHWW + lane] = cv.x;
      ob[(size_t)(wv * 4 + 1) * HHWW + lane] = cv.y;
      ob[(size_t)(wv * 4 + 2) * HHWW + lane] = cv.z;
      ob[(size_t)(wv * 4 + 3) * HHWW + lane] = cv.w;
    }
  }

  // ---- block reduce: Sum x^2 (all threads) and Sum(vt-1) (wave 0) ----
#pragma unroll
  for (int m = 1; m < 64; m <<= 1) xacc += __shfl_xor(xacc, m, 64);
  if (lane == 0) xred[wv] = xacc;
  if (wv == 0) {
#pragma unroll
    for (int m = 1; m < 64; m <<= 1) vtacc += __shfl_xor(vtacc, m, 64);
  }
  __syncthreads();
  if (tid == 0) {
    float X = 0.f;
#pragma unroll
    for (int q = 0; q < 16; ++q) X += xred[q];
    partials[blockIdx.x] = X - 2.0f * vtacc;           // Sum_p SSE_p
  }
}

// --- final loss reduce ------------------------------------------------------
__global__ __launch_bounds__(256) void vq_loss(
    const float* __restrict__ partials, float* __restrict__ loss_out)
{
  __shared__ float sred[4];
  int tid = threadIdx.x;
  float s = partials[tid];   // exactly 256 partials
#pragma unroll
  for (int m = 1; m < 64; m <<= 1) s += __shfl_xor(s, m, 64);
  if ((tid & 63) == 0) sred[tid >> 6] = s;
  __syncthreads();
  if (tid == 0)
    loss_out[0] = (sred[0] + sred[1] + sred[2] + sred[3]) * (1.25f / NPOSD);
}

extern "C" void kernel_launch(void* const* d_in, const int* in_sizes, int n_in,
                              void* d_out, int out_size, void* d_ws, size_t ws_size,
                              hipStream_t stream) {
  const float* x  = (const float*)d_in[0];
  const float* cb = (const float*)d_in[1];
  float* out      = (float*)d_out;
  float* loss_out = out + 8388608;

  char* ws = (char*)d_ws;
  unsigned short* cb_frag = (unsigned short*)(ws);      // 131072 B
  float* hneg1    = (float*)(ws + 131072);              //   4096 B
  float* partials = (float*)(ws + 135168);              //   1024 B

  vq_pre <<<4,     256, 0, stream>>>(cb, cb_frag, hneg1);
  vq_main<<<NBLK2, 1024, 0, stream>>>(x, cb_frag, hneg1, cb, out, partials);
  vq_loss<<<1,     256, 0, stream>>>(partials, loss_out);
}

// Round 7
// 69.625 us; speedup vs baseline: 2.0100x; 2.0100x over previous
//
#include <hip/hip_runtime.h>
#include <cfloat>

// ---------------------------------------------------------------------------
// VQ-VAE vector quantizer forward (MI355X / gfx950)
//   x        [32][64][64][64] f32   (B, D, H, W)
//   codebook [1024][64] f32
// out: x_q transposed back to [B,D,H,W] (8388608 f32)  +  loss scalar (1 f32)
//
// argmin_k ||x - c_k||^2  ==  argmax_k (x . c_k - ||c_k||^2/2)
// Sum_p SSE_p = Sum x^2 - 2 * Sum_p (best_score_p - 1),
//   score = dot + 1 - ||c||^2/2 (C-init trick), packed-u32 argmax (R5-proven).
//
// R7: persistent 16-wave block (1024 thr, 4 waves/SIMD), grid=256 (1/CU),
// WHOLE codebook fragment array (128 KB) staged into LDS once, amortized
// over 8 rows. Per-wave register state kept tiny (~70 VGPR) after R2/R6
// spill disasters; __launch_bounds__(1024,4) pins the budget at 128.
// Wave = (pt-half, ct-oct): 2 pos-tiles x 8 code-tiles; A held in regs,
// B ds_read once per ct; 2 barriers/row; x(r+1) issued before compute(r);
// outputs deferred to epilogue.
// ---------------------------------------------------------------------------

#define DD    64
#define HHWW  4096
#define KC    1024
#define NBLK2 256
#define RPB   8            // rows per block (2048 / 256)
#define NPOSD 8388608.0f

typedef __bf16  bf16x8 __attribute__((ext_vector_type(8)));
typedef float   f32x4  __attribute__((ext_vector_type(4)));

__device__ __forceinline__ unsigned short bf16_bits(float f) {
  unsigned u = __float_as_uint(f);
  return (unsigned short)((u + 0x7FFFu + ((u >> 16) & 1u)) >> 16);  // RNE
}

__device__ __forceinline__ void gload_lds16(const void* gsrc, void* ldst) {
  __builtin_amdgcn_global_load_lds(
      (const __attribute__((address_space(1))) unsigned int*)gsrc,
      (__attribute__((address_space(3))) unsigned int*)ldst, 16, 0, 0);
}

// --- precompute: fragment-ordered bf16 codebook + (1 - ||c||^2/2) ----------
__global__ __launch_bounds__(256) void vq_pre(
    const float* __restrict__ cb,          // [1024][64]
    unsigned short* __restrict__ cb_frag,  // [tile=64][kk=2][lane=64][e=8]
    float* __restrict__ hneg1)             // [1024] : 1 - ||c||^2/2
{
  int k = blockIdx.x * 256 + threadIdx.x;
  if (k >= KC) return;
  float c[DD];
  float sum = 0.f;
#pragma unroll
  for (int d = 0; d < DD; ++d) { c[d] = cb[k * DD + d]; sum += c[d] * c[d]; }
  hneg1[k] = 1.0f - 0.5f * sum;
  int t = k >> 4, l15 = k & 15;
#pragma unroll
  for (int kk = 0; kk < 2; ++kk)
#pragma unroll
    for (int g = 0; g < 4; ++g)
#pragma unroll
      for (int e = 0; e < 8; ++e)
        cb_frag[(((t * 2 + kk) * 64) + (g * 16 + l15)) * 8 + e] =
            bf16_bits(c[kk * 32 + g * 8 + e]);
}

// --- main: persistent fused distance-GEMM + argmin + loss + output ---------
__global__ __launch_bounds__(1024, 4) void vq_main(
    const float* __restrict__ x,
    const unsigned short* __restrict__ cb_frag,
    const float* __restrict__ hneg1,
    const float* __restrict__ cb,
    float* __restrict__ out,
    float* __restrict__ partials)
{
  __shared__ unsigned short cb_lds[65536];   // 128 KB: whole codebook frags
  __shared__ unsigned short alds[4096];      //   8 KB: current row A-frags
  __shared__ float          hneg_lds[KC];    //   4 KB
  __shared__ unsigned int   cand[8][64];     //   2 KB
  __shared__ int            idx_all[RPB][64];//   2 KB
  __shared__ float          xred[16];

  const int tid  = threadIdx.x;
  const int wv   = tid >> 6;     // 0..15
  const int lane = tid & 63;
  const int l15  = lane & 15;
  const int g    = lane >> 4;
  const int pthalf = wv >> 3;    // 0..1 : pos-tiles {2*pthalf, 2*pthalf+1}
  const int ctoct  = wv & 7;     // 0..7 : code tiles ctoct*8 .. +7

  // ---- stage whole cb_frag (128 KB) + hneg (4 KB) into LDS ----
#pragma unroll
  for (int i = 0; i < 8; ++i)
    gload_lds16((const char*)cb_frag + i * 16384 + wv * 1024 + (size_t)lane * 16,
                (char*)cb_lds + i * 16384 + wv * 1024);
  if (wv < 4)
    gload_lds16((const char*)hneg1 + wv * 1024 + (size_t)lane * 16,
                (char*)hneg_lds + wv * 1024);

  // ---- stage mapping: thread covers (w=lane, d = sd0..sd0+3) ----
  const int so  = wv >> 1, sh = wv & 1;
  const int sd0 = so * 8 + sh * 4;
  const int woff = (lane >> 4) * 1024 + (so >> 2) * 512 +
                   ((so & 3) * 16 + (lane & 15)) * 8 + sh * 4;

  const int row0 = blockIdx.x * RPB;
  const int b    = row0 >> 6;          // all 8 rows share b
  const int h0   = row0 & 63;

  float xacc = 0.f, vtacc = 0.f;

  // row 0 x slice -> regs -> pack -> LDS (write races nothing)
  float px[4];
  {
    const float* xb = x + (size_t)b * DD * HHWW + h0 * 64;
#pragma unroll
    for (int j = 0; j < 4; ++j) px[j] = xb[(size_t)(sd0 + j) * HHWW + lane];
    float s = 0.f;
    unsigned short u0 = bf16_bits(px[0]), u1 = bf16_bits(px[1]);
    unsigned short u2 = bf16_bits(px[2]), u3 = bf16_bits(px[3]);
    s = px[0]*px[0] + px[1]*px[1] + px[2]*px[2] + px[3]*px[3];
    xacc += s;
    uint2 wval;
    wval.x = (unsigned int)u0 | ((unsigned int)u1 << 16);
    wval.y = (unsigned int)u2 | ((unsigned int)u3 << 16);
    *(uint2*)(&alds[woff]) = wval;
  }
  __syncthreads();                       // B0: cb_lds, hneg_lds, alds ready

  // loop-invariant per-wave constants from LDS
  float mh[8];
#pragma unroll
  for (int i = 0; i < 8; ++i) mh[i] = hneg_lds[(ctoct * 8 + i) * 16 + l15];
  const unsigned int MASK = 0xFFFFFC00u;
  const int c0 = 1023 - ctoct * 128 - l15;   // codec_i = c0 - i*16

  for (int r = 0; r < RPB; ++r) {
    // issue next row's x loads early (land during compute)
    if (r + 1 < RPB) {
      const float* xbn = x + (size_t)b * DD * HHWW + (h0 + r + 1) * 64;
#pragma unroll
      for (int j = 0; j < 4; ++j) px[j] = xbn[(size_t)(sd0 + j) * HHWW + lane];
    }

    // ---- compute: A held (2 pos-tiles), 8 code-tiles, packed-u32 argmax ----
    bf16x8 a00, a01, a10, a11;
    {
      const char* ab = (const char*)alds + (size_t)pthalf * 4096 + (size_t)lane * 16;
      a00 = *(const bf16x8*)(ab);           // pt = pthalf*2,   kk=0
      a01 = *(const bf16x8*)(ab + 1024);    //                  kk=1
      a10 = *(const bf16x8*)(ab + 2048);    // pt = pthalf*2+1, kk=0
      a11 = *(const bf16x8*)(ab + 3072);    //                  kk=1
    }
    unsigned int best[2][4];
#pragma unroll
    for (int j = 0; j < 2; ++j)
#pragma unroll
      for (int rr = 0; rr < 4; ++rr) best[j][rr] = 0u;

#pragma unroll
    for (int i = 0; i < 8; ++i) {
      const int ct = ctoct * 8 + i;
      const char* bp = (const char*)cb_lds + (size_t)ct * 2048 + (size_t)lane * 16;
      const bf16x8 b0 = *(const bf16x8*)(bp);
      const bf16x8 b1 = *(const bf16x8*)(bp + 1024);
      const float mhv = mh[i];
      const unsigned int codec = (unsigned int)(c0 - i * 16);

      f32x4 acc0 = {mhv, mhv, mhv, mhv};
      acc0 = __builtin_amdgcn_mfma_f32_16x16x32_bf16(a00, b0, acc0, 0, 0, 0);
      acc0 = __builtin_amdgcn_mfma_f32_16x16x32_bf16(a01, b1, acc0, 0, 0, 0);
      f32x4 acc1 = {mhv, mhv, mhv, mhv};
      acc1 = __builtin_amdgcn_mfma_f32_16x16x32_bf16(a10, b0, acc1, 0, 0, 0);
      acc1 = __builtin_amdgcn_mfma_f32_16x16x32_bf16(a11, b1, acc1, 0, 0, 0);
#pragma unroll
      for (int rr = 0; rr < 4; ++rr) {   // C/D: col=l15(code), row=g*4+rr(pos)
        unsigned int p0 = (__float_as_uint(acc0[rr]) & MASK) | codec;
        best[0][rr] = best[0][rr] > p0 ? best[0][rr] : p0;
        unsigned int p1 = (__float_as_uint(acc1[rr]) & MASK) | codec;
        best[1][rr] = best[1][rr] > p1 ? best[1][rr] : p1;
      }
    }

    // cross-lane max over the 16 code columns (l15)
#pragma unroll
    for (int j = 0; j < 2; ++j)
#pragma unroll
      for (int rr = 0; rr < 4; ++rr) {
        unsigned int v = best[j][rr];
#pragma unroll
        for (int m = 1; m < 16; m <<= 1) {
          unsigned int vo = __shfl_xor(v, m, 64);
          v = v > vo ? v : vo;
        }
        if (l15 == 0)
          cand[ctoct][(pthalf * 2 + j) * 16 + g * 4 + rr] = v;
      }
    __syncthreads();                     // B1: cand ready, alds reads done

    // merge 8 ct-oct candidates per position; record idx; loss term
    if (tid < 64) {
      unsigned int v = cand[0][tid];
#pragma unroll
      for (int q = 1; q < 8; ++q) {
        unsigned int o = cand[q][tid];
        v = v > o ? v : o;
      }
      idx_all[r][tid] = 1023 - (int)(v & 1023u);
      vtacc += __uint_as_float(v & MASK) - 1.0f;   // dot - csq/2 (trunc)
    }

    // pack next row into alds (current row's reads finished at B1)
    if (r + 1 < RPB) {
      float s = px[0]*px[0] + px[1]*px[1] + px[2]*px[2] + px[3]*px[3];
      xacc += s;
      unsigned short u0 = bf16_bits(px[0]), u1 = bf16_bits(px[1]);
      unsigned short u2 = bf16_bits(px[2]), u3 = bf16_bits(px[3]);
      uint2 wval;
      wval.x = (unsigned int)u0 | ((unsigned int)u1 << 16);
      wval.y = (unsigned int)u2 | ((unsigned int)u3 << 16);
      *(uint2*)(&alds[woff]) = wval;
    }
    __syncthreads();                     // B2: alds(r+1) + idx_all[r] ready
  }

  // ---- epilogue: outputs for all 8 rows (thread = (w=lane, dquad=wv)) ----
#pragma unroll
  for (int r = 0; r < RPB; ++r) {
    const int myidx = idx_all[r][lane];
    const float4 cv = *(const float4*)(cb + (size_t)myidx * DD + wv * 4);
    float* ob = out + (size_t)b * DD * HHWW + (h0 + r) * 64;
    ob[(size_t)(wv * 4 + 0) * HHWW + lane] = cv.x;
    ob[(size_t)(wv * 4 + 1) * HHWW + lane] = cv.y;
    ob[(size_t)(wv * 4 + 2) * HHWW + lane] = cv.z;
    ob[(size_t)(wv * 4 + 3) * HHWW + lane] = cv.w;
  }

  // ---- block reduce: Sum x^2 (all threads) and Sum(vt-1) (wave 0) ----
#pragma unroll
  for (int m = 1; m < 64; m <<= 1) xacc += __shfl_xor(xacc, m, 64);
  if (lane == 0) xred[wv] = xacc;
  if (wv == 0) {
#pragma unroll
    for (int m = 1; m < 64; m <<= 1) vtacc += __shfl_xor(vtacc, m, 64);
  }
  __syncthreads();
  if (tid == 0) {
    float X = 0.f;
#pragma unroll
    for (int q = 0; q < 16; ++q) X += xred[q];
    partials[blockIdx.x] = X - 2.0f * vtacc;       // Sum_p SSE_p
  }
}

// --- final loss reduce ------------------------------------------------------
__global__ __launch_bounds__(256) void vq_loss(
    const float* __restrict__ partials, float* __restrict__ loss_out)
{
  __shared__ float sred[4];
  int tid = threadIdx.x;
  float s = partials[tid];   // exactly 256 partials
#pragma unroll
  for (int m = 1; m < 64; m <<= 1) s += __shfl_xor(s, m, 64);
  if ((tid & 63) == 0) sred[tid >> 6] = s;
  __syncthreads();
  if (tid == 0)
    loss_out[0] = (sred[0] + sred[1] + sred[2] + sred[3]) * (1.25f / NPOSD);
}

extern "C" void kernel_launch(void* const* d_in, const int* in_sizes, int n_in,
                              void* d_out, int out_size, void* d_ws, size_t ws_size,
                              hipStream_t stream) {
  const float* x  = (const float*)d_in[0];
  const float* cb = (const float*)d_in[1];
  float* out      = (float*)d_out;
  float* loss_out = out + 8388608;

  char* ws = (char*)d_ws;
  unsigned short* cb_frag = (unsigned short*)(ws);      // 131072 B
  float* hneg1    = (float*)(ws + 131072);              //   4096 B
  float* partials = (float*)(ws + 135168);              //   1024 B

  vq_pre <<<4,     256,  0, stream>>>(cb, cb_frag, hneg1);
  vq_main<<<NBLK2, 1024, 0, stream>>>(x, cb_frag, hneg1, cb, out, partials);
  vq_loss<<<1,     256,  0, stream>>>(partials, loss_out);
}